// Round 1
// baseline (923.350 us; speedup 1.0000x reference)
//
#include <hip/hip_runtime.h>
#include <hip/hip_bf16.h>
#include <stdint.h>

#define SEQ   2048
#define DIM   2048
#define HEADS 16
#define DHEAD 128
#define BATCH 4
#define MROWS (BATCH*SEQ)   // 8192

typedef short bf16x8 __attribute__((ext_vector_type(8)));
typedef float f32x4  __attribute__((ext_vector_type(4)));
typedef unsigned short u16x8 __attribute__((ext_vector_type(8)));

__device__ __forceinline__ short f2bf(float f){
  union { float fv; unsigned u; } x; x.fv = f;
  unsigned r = x.u + 0x7fffu + ((x.u >> 16) & 1u);
  return (short)(r >> 16);
}

__device__ __forceinline__ void gl_lds16(const void* g, void* l){
  __builtin_amdgcn_global_load_lds((const __attribute__((address_space(1))) void*)g,
                                   (__attribute__((address_space(3))) void*)l, 16, 0, 0);
}

// ---------------- RMSNorm (fp32) + cast to bf16 ----------------
__global__ __launch_bounds__(256) void rmsnorm_cast_k(const float* __restrict__ tok,
                                                      const float* __restrict__ w,
                                                      short* __restrict__ x){
  const int row = blockIdx.x;
  const float4* r4 = (const float4*)(tok + (size_t)row * DIM);
  float4 a = r4[threadIdx.x * 2];
  float4 b = r4[threadIdx.x * 2 + 1];
  float ss = a.x*a.x + a.y*a.y + a.z*a.z + a.w*a.w
           + b.x*b.x + b.y*b.y + b.z*b.z + b.w*b.w;
  #pragma unroll
  for (int m = 1; m < 64; m <<= 1) ss += __shfl_xor(ss, m, 64);
  __shared__ float red[4];
  if ((threadIdx.x & 63) == 0) red[threadIdx.x >> 6] = ss;
  __syncthreads();
  float tot = red[0] + red[1] + red[2] + red[3];
  float rs = rsqrtf(tot * (1.0f / DIM) + 1.1920929e-07f);
  const float4* w4 = (const float4*)w;
  float4 wa = w4[threadIdx.x * 2];
  float4 wb = w4[threadIdx.x * 2 + 1];
  u16x8 o;
  o[0] = (unsigned short)f2bf(a.x * rs * wa.x);
  o[1] = (unsigned short)f2bf(a.y * rs * wa.y);
  o[2] = (unsigned short)f2bf(a.z * rs * wa.z);
  o[3] = (unsigned short)f2bf(a.w * rs * wa.w);
  o[4] = (unsigned short)f2bf(b.x * rs * wb.x);
  o[5] = (unsigned short)f2bf(b.y * rs * wb.y);
  o[6] = (unsigned short)f2bf(b.z * rs * wb.z);
  o[7] = (unsigned short)f2bf(b.w * rs * wb.w);
  *(u16x8*)(x + (size_t)row * DIM + threadIdx.x * 8) = o;
}

// ---------------- weight cast + transpose: w[K][N] fp32 -> wt[N][K] bf16 ----------------
__global__ __launch_bounds__(256) void wtrans_k(const float* __restrict__ w,
                                                short* __restrict__ wt,
                                                int K, int N){
  __shared__ float tile[64][65];
  const int r0 = blockIdx.y * 64;   // K direction
  const int c0 = blockIdx.x * 64;   // N direction
  const int t = threadIdx.x;
  #pragma unroll
  for (int i = 0; i < 16; i++){
    int e = i * 256 + t; int r = e >> 6, c = e & 63;
    tile[r][c] = w[(size_t)(r0 + r) * N + c0 + c];
  }
  __syncthreads();
  #pragma unroll
  for (int i = 0; i < 16; i++){
    int e = i * 256 + t; int c = e >> 6, r = e & 63;
    wt[(size_t)(c0 + c) * K + r0 + r] = f2bf(tile[r][c]);
  }
}

// ---------------- V transpose: kv[b*S+n][4096] (v half) -> vt[(bh*128+d)][S] ----------------
__global__ __launch_bounds__(256) void vtrans_k(const short* __restrict__ kv,
                                                short* __restrict__ vt){
  __shared__ short tile[64][65];
  const int n0 = blockIdx.x * 64;
  const int d0 = blockIdx.y * 64;
  const int bh = blockIdx.z;
  const int b = bh >> 4, h = bh & 15;
  const int t = threadIdx.x;
  #pragma unroll
  for (int i = 0; i < 16; i++){
    int e = i * 256 + t; int r = e >> 6, c = e & 63;   // r = n, c = d
    tile[r][c] = kv[(size_t)(b * SEQ + n0 + r) * 4096 + 2048 + h * DHEAD + d0 + c];
  }
  __syncthreads();
  #pragma unroll
  for (int i = 0; i < 16; i++){
    int e = i * 256 + t; int c = e >> 6, r = e & 63;   // c = d, r = n
    vt[(size_t)(bh * DHEAD + d0 + c) * SEQ + n0 + r] = tile[r][c];
  }
}

// ---------------- GEMM: C[M][N] = A[M][K] * Bt[N][K]^T  (bf16 in, OutT out) ----------------
__device__ __forceinline__ void storeC(float* C, size_t idx, float v){ C[idx] = v; }
__device__ __forceinline__ void storeC(short* C, size_t idx, float v){ C[idx] = f2bf(v); }

template<typename OutT>
__global__ __launch_bounds__(256) void gemm_bt_k(const short* __restrict__ A,
                                                 const short* __restrict__ Bt,
                                                 OutT* __restrict__ C,
                                                 int M, int N, int K){
  __shared__ __align__(16) short As[128 * 32];
  __shared__ __align__(16) short Bs[128 * 32];
  const int m0 = blockIdx.y * 128, n0 = blockIdx.x * 128;
  const int tid = threadIdx.x, lane = tid & 63, wid = tid >> 6;
  const int wm = wid >> 1, wn = wid & 1;
  const int lrow = lane & 15, lkb = lane >> 4;
  f32x4 acc[4][4] = {};
  for (int k0 = 0; k0 < K; k0 += 32){
    __syncthreads();
    #pragma unroll
    for (int i = 0; i < 2; i++){
      int cb = (wid * 2 + i) * 64;        // wave-uniform chunk base
      int c  = cb + lane;
      // A tile: 128 rows x 32 cols; chunk c -> row c>>2, col8 (c&3)*8
      gl_lds16(A + (size_t)(m0 + (c >> 2)) * K + k0 + (c & 3) * 8, As + cb * 8);
      gl_lds16(Bt + (size_t)(n0 + (c >> 2)) * K + k0 + (c & 3) * 8, Bs + cb * 8);
    }
    __syncthreads();
    bf16x8 af[4], bfr[4];
    #pragma unroll
    for (int m = 0; m < 4; m++)
      af[m] = *(const bf16x8*)&As[(wm * 64 + m * 16 + lrow) * 32 + lkb * 8];
    #pragma unroll
    for (int n = 0; n < 4; n++)
      bfr[n] = *(const bf16x8*)&Bs[(wn * 64 + n * 16 + lrow) * 32 + lkb * 8];
    #pragma unroll
    for (int m = 0; m < 4; m++)
      #pragma unroll
      for (int n = 0; n < 4; n++)
        acc[m][n] = __builtin_amdgcn_mfma_f32_16x16x32_bf16(af[m], bfr[n], acc[m][n], 0, 0, 0);
  }
  #pragma unroll
  for (int m = 0; m < 4; m++)
    #pragma unroll
    for (int n = 0; n < 4; n++){
      int row = m0 + wm * 64 + m * 16 + (lane >> 4) * 4;
      int col = n0 + wn * 64 + n * 16 + (lane & 15);
      #pragma unroll
      for (int r = 0; r < 4; r++)
        storeC(C, (size_t)(row + r) * N + col, acc[m][n][r]);
    }
}

// ---------------- Flash attention ----------------
// q   : [b*S+n][2048] bf16 (col = h*128+d)
// kv  : [b*S+n][4096] bf16 (k half: col = h*128+d)
// vt  : [(bh*128+d)][S] bf16
// out : same layout as q (may alias q)
__global__ __launch_bounds__(256) void attn_k(const short* __restrict__ q,
                                              const short* __restrict__ kv,
                                              const short* __restrict__ vt,
                                              short* __restrict__ out){
  __shared__ __align__(16) short Ks[64 * 128];
  __shared__ __align__(16) short Vts[128 * 64];
  __shared__ __align__(16) short Pl[4 * 32 * 64];
  const int qt = blockIdx.x, bh = blockIdx.y;
  const int b = bh >> 4, h = bh & 15;
  const int tid = threadIdx.x, lane = tid & 63, wid = tid >> 6;
  const int lrow = lane & 15, lkb = lane >> 4;
  const int qrow0 = qt * 128 + wid * 32;
  const float scale = 0.08838834764831845f;   // 128^-0.5

  bf16x8 qf[2][4];
  #pragma unroll
  for (int mf = 0; mf < 2; mf++)
    #pragma unroll
    for (int ks = 0; ks < 4; ks++)
      qf[mf][ks] = *(const bf16x8*)(q + (size_t)(b * SEQ + qrow0 + mf * 16 + lrow) * DIM
                                      + h * DHEAD + ks * 32 + lkb * 8);

  f32x4 acc[2][8] = {};
  float m_st[2][4], l_st[2][4];
  #pragma unroll
  for (int mf = 0; mf < 2; mf++)
    #pragma unroll
    for (int r = 0; r < 4; r++){ m_st[mf][r] = -1e30f; l_st[mf][r] = 0.0f; }

  for (int kt = 0; kt < SEQ / 64; kt++){
    __syncthreads();
    #pragma unroll
    for (int i = 0; i < 4; i++){
      int cb = (wid * 4 + i) * 64;
      int c  = cb + lane;
      // K tile: 64 keys x 128 d; chunk c -> key c>>4, d8 (c&15)*8
      gl_lds16(kv + (size_t)(b * SEQ + kt * 64 + (c >> 4)) * 4096 + h * DHEAD + (c & 15) * 8,
               Ks + cb * 8);
      // Vt tile: 128 d x 64 keys; chunk c -> d c>>3, key8 (c&7)*8
      gl_lds16(vt + (size_t)(bh * DHEAD + (c >> 3)) * SEQ + kt * 64 + (c & 7) * 8,
               Vts + cb * 8);
    }
    __syncthreads();

    // QK^T: S[2 mf][4 nf] frags, K-dim = d (4 steps of 32)
    f32x4 s[2][4];
    #pragma unroll
    for (int mf = 0; mf < 2; mf++)
      #pragma unroll
      for (int nf = 0; nf < 4; nf++){
        f32x4 t = {0.f, 0.f, 0.f, 0.f};
        #pragma unroll
        for (int ks = 0; ks < 4; ks++){
          bf16x8 kf = *(const bf16x8*)&Ks[(nf * 16 + lrow) * 128 + ks * 32 + lkb * 8];
          t = __builtin_amdgcn_mfma_f32_16x16x32_bf16(qf[mf][ks], kf, t, 0, 0, 0);
        }
        s[mf][nf] = t * scale;
      }

    // online softmax (rows = lkb*4 + r per lane, spread over 16 lanes of same lkb)
    #pragma unroll
    for (int mf = 0; mf < 2; mf++)
      #pragma unroll
      for (int r = 0; r < 4; r++){
        float mx = s[mf][0][r];
        #pragma unroll
        for (int nf = 1; nf < 4; nf++) mx = fmaxf(mx, s[mf][nf][r]);
        #pragma unroll
        for (int o = 1; o < 16; o <<= 1) mx = fmaxf(mx, __shfl_xor(mx, o, 64));
        float mnew = fmaxf(m_st[mf][r], mx);
        float alpha = __expf(m_st[mf][r] - mnew);
        m_st[mf][r] = mnew;
        #pragma unroll
        for (int nf = 0; nf < 8; nf++) acc[mf][nf][r] *= alpha;
        float ps = 0.f;
        #pragma unroll
        for (int nf = 0; nf < 4; nf++){
          float p = __expf(s[mf][nf][r] - mnew);
          s[mf][nf][r] = p;
          ps += p;
        }
        #pragma unroll
        for (int o = 1; o < 16; o <<= 1) ps += __shfl_xor(ps, o, 64);
        l_st[mf][r] = l_st[mf][r] * alpha + ps;
      }

    // P -> LDS (bf16), per-wave region
    #pragma unroll
    for (int mf = 0; mf < 2; mf++)
      #pragma unroll
      for (int nf = 0; nf < 4; nf++)
        #pragma unroll
        for (int r = 0; r < 4; r++){
          int row = mf * 16 + lkb * 4 + r;
          int col = nf * 16 + lrow;
          Pl[wid * 2048 + row * 64 + col] = f2bf(s[mf][nf][r]);
        }

    // PV: out[32 rows][128 d] += P[32][64] * V[64][128]
    bf16x8 pa[2][2];
    #pragma unroll
    for (int mf = 0; mf < 2; mf++)
      #pragma unroll
      for (int kk = 0; kk < 2; kk++)
        pa[mf][kk] = *(const bf16x8*)&Pl[wid * 2048 + (mf * 16 + lrow) * 64 + kk * 32 + lkb * 8];
    #pragma unroll
    for (int nf = 0; nf < 8; nf++)
      #pragma unroll
      for (int kk = 0; kk < 2; kk++){
        bf16x8 vb = *(const bf16x8*)&Vts[(nf * 16 + lrow) * 64 + kk * 32 + lkb * 8];
        acc[0][nf] = __builtin_amdgcn_mfma_f32_16x16x32_bf16(pa[0][kk], vb, acc[0][nf], 0, 0, 0);
        acc[1][nf] = __builtin_amdgcn_mfma_f32_16x16x32_bf16(pa[1][kk], vb, acc[1][nf], 0, 0, 0);
      }
  }

  // epilogue: divide by l, write bf16
  #pragma unroll
  for (int mf = 0; mf < 2; mf++)
    #pragma unroll
    for (int nf = 0; nf < 8; nf++)
      #pragma unroll
      for (int r = 0; r < 4; r++){
        float v = acc[mf][nf][r] / l_st[mf][r];
        int row = qrow0 + mf * 16 + lkb * 4 + r;
        int col = h * DHEAD + nf * 16 + lrow;
        out[(size_t)(b * SEQ + row) * DIM + col] = f2bf(v);
      }
}

// ---------------- launch ----------------
extern "C" void kernel_launch(void* const* d_in, const int* in_sizes, int n_in,
                              void* d_out, int out_size, void* d_ws, size_t ws_size,
                              hipStream_t stream) {
  (void)in_sizes; (void)n_in; (void)out_size; (void)ws_size;
  const float* tokens = (const float*)d_in[0];
  const float* normw  = (const float*)d_in[1];
  const float* wq     = (const float*)d_in[2];
  const float* wkv    = (const float*)d_in[3];
  const float* wout   = (const float*)d_in[4];
  float* outp = (float*)d_out;
  char* ws = (char*)d_ws;

  short* x     = (short*)(ws + 0);                    // 8192*2048*2   = 33554432
  short* wqt   = (short*)(ws + 33554432);             // 2048*2048*2   = 8388608
  short* wkvt  = (short*)(ws + 41943040);             // 4096*2048*2   = 16777216
  short* woutt = (short*)(ws + 58720256);             // 2048*2048*2   = 8388608
  short* qb    = (short*)(ws + 67108864);             // 8192*2048*2   = 33554432 (also attn out)
  short* kvb   = (short*)(ws + 100663296);            // 8192*4096*2   = 67108864
  short* vtb   = (short*)(ws + 167772160);            // 64*128*2048*2 = 33554432  (end 201326592)

  rmsnorm_cast_k<<<dim3(MROWS), dim3(256), 0, stream>>>(tokens, normw, x);
  wtrans_k<<<dim3(2048/64, 2048/64), dim3(256), 0, stream>>>(wq,   wqt,   2048, 2048);
  wtrans_k<<<dim3(4096/64, 2048/64), dim3(256), 0, stream>>>(wkv,  wkvt,  2048, 4096);
  wtrans_k<<<dim3(2048/64, 2048/64), dim3(256), 0, stream>>>(wout, woutt, 2048, 2048);
  gemm_bt_k<short><<<dim3(2048/128, MROWS/128), dim3(256), 0, stream>>>(x, wqt,  qb,  MROWS, 2048, 2048);
  gemm_bt_k<short><<<dim3(4096/128, MROWS/128), dim3(256), 0, stream>>>(x, wkvt, kvb, MROWS, 4096, 2048);
  vtrans_k<<<dim3(SEQ/64, DHEAD/64, BATCH*HEADS), dim3(256), 0, stream>>>(kvb, vtb);
  attn_k<<<dim3(SEQ/128, BATCH*HEADS), dim3(256), 0, stream>>>(qb, kvb, vtb, qb);
  gemm_bt_k<float><<<dim3(2048/128, MROWS/128), dim3(256), 0, stream>>>(qb, woutt, outp, MROWS, 2048, 2048);
}

// Round 2
// 795.146 us; speedup vs baseline: 1.1612x; 1.1612x over previous
//
#include <hip/hip_runtime.h>
#include <hip/hip_bf16.h>
#include <stdint.h>

#define SEQ   2048
#define DIM   2048
#define HEADS 16
#define DHEAD 128
#define BATCH 4
#define MROWS (BATCH*SEQ)   // 8192

typedef short bf16x8 __attribute__((ext_vector_type(8)));
typedef float f32x4  __attribute__((ext_vector_type(4)));
typedef unsigned short u16x8 __attribute__((ext_vector_type(8)));
typedef unsigned int u32x4 __attribute__((ext_vector_type(4)));

__device__ __forceinline__ short f2bf(float f){
  union { float fv; unsigned u; } x; x.fv = f;
  unsigned r = x.u + 0x7fffu + ((x.u >> 16) & 1u);
  return (short)(r >> 16);
}

__device__ __forceinline__ unsigned cvtpk(float lo, float hi){
  unsigned r; asm("v_cvt_pk_bf16_f32 %0, %1, %2" : "=v"(r) : "v"(lo), "v"(hi)); return r;
}

__device__ __forceinline__ void gl_lds16(const void* g, void* l){
  __builtin_amdgcn_global_load_lds((const __attribute__((address_space(1))) void*)g,
                                   (__attribute__((address_space(3))) void*)l, 16, 0, 0);
}

// ---------------- RMSNorm (fp32) + cast to bf16 ----------------
__global__ __launch_bounds__(256) void rmsnorm_cast_k(const float* __restrict__ tok,
                                                      const float* __restrict__ w,
                                                      short* __restrict__ x){
  const int row = blockIdx.x;
  const float4* r4 = (const float4*)(tok + (size_t)row * DIM);
  float4 a = r4[threadIdx.x * 2];
  float4 b = r4[threadIdx.x * 2 + 1];
  float ss = a.x*a.x + a.y*a.y + a.z*a.z + a.w*a.w
           + b.x*b.x + b.y*b.y + b.z*b.z + b.w*b.w;
  #pragma unroll
  for (int m = 1; m < 64; m <<= 1) ss += __shfl_xor(ss, m, 64);
  __shared__ float red[4];
  if ((threadIdx.x & 63) == 0) red[threadIdx.x >> 6] = ss;
  __syncthreads();
  float tot = red[0] + red[1] + red[2] + red[3];
  float rs = rsqrtf(tot * (1.0f / DIM) + 1.1920929e-07f);
  const float4* w4 = (const float4*)w;
  float4 wa = w4[threadIdx.x * 2];
  float4 wb = w4[threadIdx.x * 2 + 1];
  u16x8 o;
  o[0] = (unsigned short)f2bf(a.x * rs * wa.x);
  o[1] = (unsigned short)f2bf(a.y * rs * wa.y);
  o[2] = (unsigned short)f2bf(a.z * rs * wa.z);
  o[3] = (unsigned short)f2bf(a.w * rs * wa.w);
  o[4] = (unsigned short)f2bf(b.x * rs * wb.x);
  o[5] = (unsigned short)f2bf(b.y * rs * wb.y);
  o[6] = (unsigned short)f2bf(b.z * rs * wb.z);
  o[7] = (unsigned short)f2bf(b.w * rs * wb.w);
  *(u16x8*)(x + (size_t)row * DIM + threadIdx.x * 8) = o;
}

// ---------------- weight cast + transpose: w[K][N] fp32 -> wt[N][K] bf16 ----------------
__global__ __launch_bounds__(256) void wtrans_k(const float* __restrict__ w,
                                                short* __restrict__ wt,
                                                int K, int N){
  __shared__ float tile[64][65];
  const int r0 = blockIdx.y * 64;   // K direction
  const int c0 = blockIdx.x * 64;   // N direction
  const int t = threadIdx.x;
  #pragma unroll
  for (int i = 0; i < 16; i++){
    int e = i * 256 + t; int r = e >> 6, c = e & 63;
    tile[r][c] = w[(size_t)(r0 + r) * N + c0 + c];
  }
  __syncthreads();
  #pragma unroll
  for (int i = 0; i < 16; i++){
    int e = i * 256 + t; int c = e >> 6, r = e & 63;
    wt[(size_t)(c0 + c) * K + r0 + r] = f2bf(tile[r][c]);
  }
}

// ---------------- V transpose: kv[b*S+n][4096] (v half) -> vt[(bh*128+d)][S] ----------------
__global__ __launch_bounds__(256) void vtrans_k(const short* __restrict__ kv,
                                                short* __restrict__ vt){
  __shared__ short tile[64][65];
  const int n0 = blockIdx.x * 64;
  const int d0 = blockIdx.y * 64;
  const int bh = blockIdx.z;
  const int b = bh >> 4, h = bh & 15;
  const int t = threadIdx.x;
  #pragma unroll
  for (int i = 0; i < 16; i++){
    int e = i * 256 + t; int r = e >> 6, c = e & 63;   // r = n, c = d
    tile[r][c] = kv[(size_t)(b * SEQ + n0 + r) * 4096 + 2048 + h * DHEAD + d0 + c];
  }
  __syncthreads();
  #pragma unroll
  for (int i = 0; i < 16; i++){
    int e = i * 256 + t; int c = e >> 6, r = e & 63;   // c = d, r = n
    vt[(size_t)(bh * DHEAD + d0 + c) * SEQ + n0 + r] = tile[r][c];
  }
}

// ---------------- GEMM: C[M][N] = A[M][K] * Bt[N][K]^T  (bf16 in, OutT out) ----------------
__device__ __forceinline__ void storeC(float* C, size_t idx, float v){ C[idx] = v; }
__device__ __forceinline__ void storeC(short* C, size_t idx, float v){ C[idx] = f2bf(v); }

template<typename OutT>
__global__ __launch_bounds__(256) void gemm_bt_k(const short* __restrict__ A,
                                                 const short* __restrict__ Bt,
                                                 OutT* __restrict__ C,
                                                 int M, int N, int K){
  __shared__ __align__(16) short As[128 * 32];
  __shared__ __align__(16) short Bs[128 * 32];
  const int m0 = blockIdx.y * 128, n0 = blockIdx.x * 128;
  const int tid = threadIdx.x, lane = tid & 63, wid = tid >> 6;
  const int wm = wid >> 1, wn = wid & 1;
  const int lrow = lane & 15, lkb = lane >> 4;
  f32x4 acc[4][4] = {};
  for (int k0 = 0; k0 < K; k0 += 32){
    __syncthreads();
    #pragma unroll
    for (int i = 0; i < 2; i++){
      int cb = (wid * 2 + i) * 64;        // wave-uniform chunk base
      int c  = cb + lane;
      gl_lds16(A + (size_t)(m0 + (c >> 2)) * K + k0 + (c & 3) * 8, As + cb * 8);
      gl_lds16(Bt + (size_t)(n0 + (c >> 2)) * K + k0 + (c & 3) * 8, Bs + cb * 8);
    }
    __syncthreads();
    bf16x8 af[4], bfr[4];
    #pragma unroll
    for (int m = 0; m < 4; m++)
      af[m] = *(const bf16x8*)&As[(wm * 64 + m * 16 + lrow) * 32 + lkb * 8];
    #pragma unroll
    for (int n = 0; n < 4; n++)
      bfr[n] = *(const bf16x8*)&Bs[(wn * 64 + n * 16 + lrow) * 32 + lkb * 8];
    #pragma unroll
    for (int m = 0; m < 4; m++)
      #pragma unroll
      for (int n = 0; n < 4; n++)
        acc[m][n] = __builtin_amdgcn_mfma_f32_16x16x32_bf16(af[m], bfr[n], acc[m][n], 0, 0, 0);
  }
  #pragma unroll
  for (int m = 0; m < 4; m++)
    #pragma unroll
    for (int n = 0; n < 4; n++){
      int row = m0 + wm * 64 + m * 16 + (lane >> 4) * 4;
      int col = n0 + wn * 64 + n * 16 + (lane & 15);
      #pragma unroll
      for (int r = 0; r < 4; r++)
        storeC(C, (size_t)(row + r) * N + col, acc[m][n][r]);
    }
}

// ---------------- Flash attention (swapped QK^T, in-register softmax, swizzled LDS) ----------
// q   : [b*S+n][2048] bf16 (col = h*128+d)
// kv  : [b*S+n][4096] bf16 (k half: col = h*128+d)
// vt  : [(bh*128+d)][S] bf16
// out : same layout as q (may alias q)
__global__ __launch_bounds__(256) void attn_k(const short* __restrict__ q,
                                              const short* __restrict__ kv,
                                              const short* __restrict__ vt,
                                              short* __restrict__ out){
  // K tile: [64 keys][128 d], 16B chunks XOR-swizzled by (key&7)
  // Vt tile: [128 d][64 keys], 16B chunks XOR-swizzled by (d&7)
  __shared__ __align__(16) short Ks[2][64 * 128];
  __shared__ __align__(16) short Vts[2][128 * 64];
  const int qt = blockIdx.x, bh = blockIdx.y;
  const int b = bh >> 4, h = bh & 15;
  const int tid = threadIdx.x, lane = tid & 63, wid = tid >> 6;
  const int lrow = lane & 15, lkb = lane >> 4;
  const int qrow0 = qt * 128 + wid * 32;
  const float scale = 0.08838834764831845f;   // 128^-0.5
  const int NT = SEQ / 64;

  // Q b-frags: qf[mf][ks] = Q[q = qrow0+mf*16+lrow][d = ks*32+lkb*8 ..]
  bf16x8 qf[2][4];
  #pragma unroll
  for (int mf = 0; mf < 2; mf++)
    #pragma unroll
    for (int ks = 0; ks < 4; ks++)
      qf[mf][ks] = *(const bf16x8*)(q + (size_t)(b * SEQ + qrow0 + mf * 16 + lrow) * DIM
                                      + h * DHEAD + ks * 32 + lkb * 8);

  f32x4 acc[2][8] = {};
  float m_st[2] = {-1e30f, -1e30f};
  float l_st[2] = {0.0f, 0.0f};

  auto stage = [&](int kt2, int bs){
    #pragma unroll
    for (int i = 0; i < 4; i++){
      int cb = (wid * 4 + i) * 64;
      int c  = cb + lane;
      int kr = c >> 4, kj = (c & 15) ^ (kr & 7);          // K: row kr, src chunk kj
      gl_lds16(kv + (size_t)(b * SEQ + kt2 * 64 + kr) * 4096 + h * DHEAD + kj * 8,
               &Ks[bs][cb * 8]);
      int vr = c >> 3, vj = (c & 7) ^ (vr & 7);           // Vt: row vr, src chunk vj
      gl_lds16(vt + (size_t)(bh * DHEAD + vr) * SEQ + kt2 * 64 + vj * 8,
               &Vts[bs][cb * 8]);
    }
  };

  stage(0, 0);
  int cur = 0;

  for (int kt = 0; kt < NT; kt++){
    if (kt + 1 < NT){
      stage(kt + 1, cur ^ 1);
      asm volatile("s_waitcnt vmcnt(8)" ::: "memory");
    } else {
      asm volatile("s_waitcnt vmcnt(0)" ::: "memory");
    }
    __builtin_amdgcn_s_barrier();

    const short* Kb = &Ks[cur][0];
    const short* Vb = &Vts[cur][0];

    // QK^T swapped: t[mf][nf] = S^T frag -> lane holds P[q=lrow][key = nf*16+lkb*4+r]
    f32x4 t[2][4];
    #pragma unroll
    for (int nf = 0; nf < 4; nf++){
      f32x4 t0 = {0.f, 0.f, 0.f, 0.f}, t1 = {0.f, 0.f, 0.f, 0.f};
      int row = nf * 16 + lrow;
      #pragma unroll
      for (int ks = 0; ks < 4; ks++){
        bf16x8 kf = *(const bf16x8*)&Kb[row * 128 + (((ks * 4 + lkb) ^ (row & 7)) * 8)];
        t0 = __builtin_amdgcn_mfma_f32_16x16x32_bf16(kf, qf[0][ks], t0, 0, 0, 0);
        t1 = __builtin_amdgcn_mfma_f32_16x16x32_bf16(kf, qf[1][ks], t1, 0, 0, 0);
      }
      t[0][nf] = t0; t[1][nf] = t1;
    }

    // online softmax fully in-register (per lane: q = lrow, 16 keys)
    unsigned pk[2][8];
    #pragma unroll
    for (int mf = 0; mf < 2; mf++){
      float mx = -1e30f;
      #pragma unroll
      for (int nf = 0; nf < 4; nf++){
        t[mf][nf] *= scale;
        #pragma unroll
        for (int r = 0; r < 4; r++) mx = fmaxf(mx, t[mf][nf][r]);
      }
      mx = fmaxf(mx, __shfl_xor(mx, 16));
      mx = fmaxf(mx, __shfl_xor(mx, 32));
      float mnew = fmaxf(m_st[mf], mx);
      float alpha = __expf(m_st[mf] - mnew);
      m_st[mf] = mnew;
      float ps = 0.f;
      #pragma unroll
      for (int nf = 0; nf < 4; nf++){
        #pragma unroll
        for (int r = 0; r < 4; r++){
          float p = __expf(t[mf][nf][r] - mnew);
          t[mf][nf][r] = p;
          ps += p;
        }
        pk[mf][nf * 2 + 0] = cvtpk(t[mf][nf][0], t[mf][nf][1]);
        pk[mf][nf * 2 + 1] = cvtpk(t[mf][nf][2], t[mf][nf][3]);
      }
      ps += __shfl_xor(ps, 16);
      ps += __shfl_xor(ps, 32);
      l_st[mf] = l_st[mf] * alpha + ps;
      #pragma unroll
      for (int r = 0; r < 4; r++){
        float ar = __shfl(alpha, lkb * 4 + r);
        #pragma unroll
        for (int nf = 0; nf < 8; nf++) acc[mf][nf][r] *= ar;
      }
    }

    // build PV A-frags via shfl exchange, then PV MFMAs
    #pragma unroll
    for (int kk = 0; kk < 2; kk++){
      bf16x8 pa[2];
      int srcA = lrow + ((lane & 16) << 1);   // lrow + 32*(lkb&1)
      #pragma unroll
      for (int mf = 0; mf < 2; mf++){
        u32x4 wv;
        #pragma unroll
        for (int i = 0; i < 4; i++){
          int src = srcA + ((i >> 1) << 4);
          unsigned vL = __shfl((int)pk[mf][(2 * kk    ) * 2 + (i & 1)], src);
          unsigned vH = __shfl((int)pk[mf][(2 * kk + 1) * 2 + (i & 1)], src);
          wv[i] = (lkb >= 2) ? vH : vL;
        }
        union { u32x4 u; bf16x8 v; } c_; c_.u = wv; pa[mf] = c_.v;
      }
      #pragma unroll
      for (int nf = 0; nf < 8; nf++){
        int row = nf * 16 + lrow;
        bf16x8 vb = *(const bf16x8*)&Vb[row * 64 + (((kk * 4 + lkb) ^ (row & 7)) * 8)];
        acc[0][nf] = __builtin_amdgcn_mfma_f32_16x16x32_bf16(pa[0], vb, acc[0][nf], 0, 0, 0);
        acc[1][nf] = __builtin_amdgcn_mfma_f32_16x16x32_bf16(pa[1], vb, acc[1][nf], 0, 0, 0);
      }
    }

    asm volatile("s_waitcnt lgkmcnt(0)" ::: "memory");
    __builtin_amdgcn_s_barrier();
    cur ^= 1;
  }

  // epilogue: divide by l (broadcast to acc rows), write bf16
  #pragma unroll
  for (int mf = 0; mf < 2; mf++)
    #pragma unroll
    for (int r = 0; r < 4; r++){
      float inv = 1.0f / __shfl(l_st[mf], lkb * 4 + r);
      #pragma unroll
      for (int nf = 0; nf < 8; nf++){
        int row = qrow0 + mf * 16 + lkb * 4 + r;
        int col = h * DHEAD + nf * 16 + lrow;
        out[(size_t)(b * SEQ + row) * DIM + col] = f2bf(acc[mf][nf][r] * inv);
      }
    }
}

// ---------------- launch ----------------
extern "C" void kernel_launch(void* const* d_in, const int* in_sizes, int n_in,
                              void* d_out, int out_size, void* d_ws, size_t ws_size,
                              hipStream_t stream) {
  (void)in_sizes; (void)n_in; (void)out_size; (void)ws_size;
  const float* tokens = (const float*)d_in[0];
  const float* normw  = (const float*)d_in[1];
  const float* wq     = (const float*)d_in[2];
  const float* wkv    = (const float*)d_in[3];
  const float* wout   = (const float*)d_in[4];
  float* outp = (float*)d_out;
  char* ws = (char*)d_ws;

  short* x     = (short*)(ws + 0);                    // 8192*2048*2   = 33554432
  short* wqt   = (short*)(ws + 33554432);             // 2048*2048*2   = 8388608
  short* wkvt  = (short*)(ws + 41943040);             // 4096*2048*2   = 16777216
  short* woutt = (short*)(ws + 58720256);             // 2048*2048*2   = 8388608
  short* qb    = (short*)(ws + 67108864);             // 8192*2048*2   = 33554432 (also attn out)
  short* kvb   = (short*)(ws + 100663296);            // 8192*4096*2   = 67108864
  short* vtb   = (short*)(ws + 167772160);            // 64*128*2048*2 = 33554432  (end 201326592)

  rmsnorm_cast_k<<<dim3(MROWS), dim3(256), 0, stream>>>(tokens, normw, x);
  wtrans_k<<<dim3(2048/64, 2048/64), dim3(256), 0, stream>>>(wq,   wqt,   2048, 2048);
  wtrans_k<<<dim3(4096/64, 2048/64), dim3(256), 0, stream>>>(wkv,  wkvt,  2048, 4096);
  wtrans_k<<<dim3(2048/64, 2048/64), dim3(256), 0, stream>>>(wout, woutt, 2048, 2048);
  gemm_bt_k<short><<<dim3(2048/128, MROWS/128), dim3(256), 0, stream>>>(x, wqt,  qb,  MROWS, 2048, 2048);
  gemm_bt_k<short><<<dim3(4096/128, MROWS/128), dim3(256), 0, stream>>>(x, wkvt, kvb, MROWS, 4096, 2048);
  vtrans_k<<<dim3(SEQ/64, DHEAD/64, BATCH*HEADS), dim3(256), 0, stream>>>(kvb, vtb);
  attn_k<<<dim3(SEQ/128, BATCH*HEADS), dim3(256), 0, stream>>>(qb, kvb, vtb, qb);
  gemm_bt_k<float><<<dim3(2048/128, MROWS/128), dim3(256), 0, stream>>>(qb, woutt, outp, MROWS, 2048, 2048);
}

// Round 3
// 686.133 us; speedup vs baseline: 1.3457x; 1.1589x over previous
//
#include <hip/hip_runtime.h>
#include <hip/hip_bf16.h>
#include <stdint.h>

#define SEQ   2048
#define DIM   2048
#define HEADS 16
#define DHEAD 128
#define BATCH 4
#define MROWS (BATCH*SEQ)   // 8192

typedef short bf16x8 __attribute__((ext_vector_type(8)));
typedef float f32x4  __attribute__((ext_vector_type(4)));
typedef float f32x16 __attribute__((ext_vector_type(16)));
typedef unsigned short u16x8 __attribute__((ext_vector_type(8)));
typedef unsigned int u32x4 __attribute__((ext_vector_type(4)));

__device__ __forceinline__ short f2bf(float f){
  union { float fv; unsigned u; } x; x.fv = f;
  unsigned r = x.u + 0x7fffu + ((x.u >> 16) & 1u);
  return (short)(r >> 16);
}

__device__ __forceinline__ unsigned cvtpk(float lo, float hi){
  unsigned r; asm("v_cvt_pk_bf16_f32 %0, %1, %2" : "=v"(r) : "v"(lo), "v"(hi)); return r;
}

__device__ __forceinline__ float exp2a(float x){
#if __has_builtin(__builtin_amdgcn_exp2f)
  return __builtin_amdgcn_exp2f(x);
#else
  return exp2f(x);
#endif
}

__device__ __forceinline__ void gl_lds16(const void* g, void* l){
  __builtin_amdgcn_global_load_lds((const __attribute__((address_space(1))) void*)g,
                                   (__attribute__((address_space(3))) void*)l, 16, 0, 0);
}

// ---------------- RMSNorm (fp32) + cast to bf16 ----------------
__global__ __launch_bounds__(256) void rmsnorm_cast_k(const float* __restrict__ tok,
                                                      const float* __restrict__ w,
                                                      short* __restrict__ x){
  const int row = blockIdx.x;
  const float4* r4 = (const float4*)(tok + (size_t)row * DIM);
  float4 a = r4[threadIdx.x * 2];
  float4 b = r4[threadIdx.x * 2 + 1];
  float ss = a.x*a.x + a.y*a.y + a.z*a.z + a.w*a.w
           + b.x*b.x + b.y*b.y + b.z*b.z + b.w*b.w;
  #pragma unroll
  for (int m = 1; m < 64; m <<= 1) ss += __shfl_xor(ss, m, 64);
  __shared__ float red[4];
  if ((threadIdx.x & 63) == 0) red[threadIdx.x >> 6] = ss;
  __syncthreads();
  float tot = red[0] + red[1] + red[2] + red[3];
  float rs = rsqrtf(tot * (1.0f / DIM) + 1.1920929e-07f);
  const float4* w4 = (const float4*)w;
  float4 wa = w4[threadIdx.x * 2];
  float4 wb = w4[threadIdx.x * 2 + 1];
  u16x8 o;
  o[0] = (unsigned short)f2bf(a.x * rs * wa.x);
  o[1] = (unsigned short)f2bf(a.y * rs * wa.y);
  o[2] = (unsigned short)f2bf(a.z * rs * wa.z);
  o[3] = (unsigned short)f2bf(a.w * rs * wa.w);
  o[4] = (unsigned short)f2bf(b.x * rs * wb.x);
  o[5] = (unsigned short)f2bf(b.y * rs * wb.y);
  o[6] = (unsigned short)f2bf(b.z * rs * wb.z);
  o[7] = (unsigned short)f2bf(b.w * rs * wb.w);
  *(u16x8*)(x + (size_t)row * DIM + threadIdx.x * 8) = o;
}

// ---------------- weight cast + transpose: w[K][N] fp32 -> wt[N][K] bf16 ----------------
__global__ __launch_bounds__(256) void wtrans_k(const float* __restrict__ w,
                                                short* __restrict__ wt,
                                                int K, int N){
  __shared__ float tile[64][65];
  const int r0 = blockIdx.y * 64;   // K direction
  const int c0 = blockIdx.x * 64;   // N direction
  const int t = threadIdx.x;
  #pragma unroll
  for (int i = 0; i < 16; i++){
    int e = i * 256 + t; int r = e >> 6, c = e & 63;
    tile[r][c] = w[(size_t)(r0 + r) * N + c0 + c];
  }
  __syncthreads();
  #pragma unroll
  for (int i = 0; i < 16; i++){
    int e = i * 256 + t; int c = e >> 6, r = e & 63;
    wt[(size_t)(c0 + c) * K + r0 + r] = f2bf(tile[r][c]);
  }
}

// ---------------- V transpose: kv[b*S+n][4096] (v half) -> vt[(bh*128+d)][S] ----------------
__global__ __launch_bounds__(256) void vtrans_k(const short* __restrict__ kv,
                                                short* __restrict__ vt){
  __shared__ short tile[64][65];
  const int n0 = blockIdx.x * 64;
  const int d0 = blockIdx.y * 64;
  const int bh = blockIdx.z;
  const int b = bh >> 4, h = bh & 15;
  const int t = threadIdx.x;
  #pragma unroll
  for (int i = 0; i < 16; i++){
    int e = i * 256 + t; int r = e >> 6, c = e & 63;   // r = n, c = d
    tile[r][c] = kv[(size_t)(b * SEQ + n0 + r) * 4096 + 2048 + h * DHEAD + d0 + c];
  }
  __syncthreads();
  #pragma unroll
  for (int i = 0; i < 16; i++){
    int e = i * 256 + t; int c = e >> 6, r = e & 63;   // c = d, r = n
    vt[(size_t)(bh * DHEAD + d0 + c) * SEQ + n0 + r] = tile[r][c];
  }
}

// ---------------- GEMM: C[M][N] = A[M][K] * Bt[N][K]^T  (bf16 in, OutT out) ----------------
__device__ __forceinline__ void storeC(float* C, size_t idx, float v){ C[idx] = v; }
__device__ __forceinline__ void storeC(short* C, size_t idx, float v){ C[idx] = f2bf(v); }

template<typename OutT>
__global__ __launch_bounds__(256) void gemm_bt_k(const short* __restrict__ A,
                                                 const short* __restrict__ Bt,
                                                 OutT* __restrict__ C,
                                                 int M, int N, int K){
  __shared__ __align__(16) short As[128 * 32];
  __shared__ __align__(16) short Bs[128 * 32];
  const int m0 = blockIdx.y * 128, n0 = blockIdx.x * 128;
  const int tid = threadIdx.x, lane = tid & 63, wid = tid >> 6;
  const int wm = wid >> 1, wn = wid & 1;
  const int lrow = lane & 15, lkb = lane >> 4;
  f32x4 acc[4][4] = {};
  for (int k0 = 0; k0 < K; k0 += 32){
    __syncthreads();
    #pragma unroll
    for (int i = 0; i < 2; i++){
      int cb = (wid * 2 + i) * 64;        // wave-uniform chunk base
      int c  = cb + lane;
      gl_lds16(A + (size_t)(m0 + (c >> 2)) * K + k0 + (c & 3) * 8, As + cb * 8);
      gl_lds16(Bt + (size_t)(n0 + (c >> 2)) * K + k0 + (c & 3) * 8, Bs + cb * 8);
    }
    __syncthreads();
    bf16x8 af[4], bfr[4];
    #pragma unroll
    for (int m = 0; m < 4; m++)
      af[m] = *(const bf16x8*)&As[(wm * 64 + m * 16 + lrow) * 32 + lkb * 8];
    #pragma unroll
    for (int n = 0; n < 4; n++)
      bfr[n] = *(const bf16x8*)&Bs[(wn * 64 + n * 16 + lrow) * 32 + lkb * 8];
    #pragma unroll
    for (int m = 0; m < 4; m++)
      #pragma unroll
      for (int n = 0; n < 4; n++)
        acc[m][n] = __builtin_amdgcn_mfma_f32_16x16x32_bf16(af[m], bfr[n], acc[m][n], 0, 0, 0);
  }
  #pragma unroll
  for (int m = 0; m < 4; m++)
    #pragma unroll
    for (int n = 0; n < 4; n++){
      int row = m0 + wm * 64 + m * 16 + (lane >> 4) * 4;
      int col = n0 + wn * 64 + n * 16 + (lane & 15);
      #pragma unroll
      for (int r = 0; r < 4; r++)
        storeC(C, (size_t)(row + r) * N + col, acc[m][n][r]);
    }
}

// ---------------- Flash attention: 4 waves x 32 q-rows, 32x32x16 MFMA, swapped QK^T ---------
// q   : [b*S+n][2048] bf16 (col = h*128+d)
// kv  : [b*S+n][4096] bf16 (k half: col = h*128+d)
// vt  : [(bh*128+d)][S] bf16
// out : same layout as q (aliases q; each block reads only its own rows before writing)
//
// MFMA 32x32x16 layouts (derived from verified 16x16x32 pattern + m74/m101 C/D):
//   A: row = lane&31, k = (lane>>5)*8 + e (8 contiguous)
//   B: col = lane&31, k = (lane>>5)*8 + e
//   D: col = lane&31, row = (reg&3) + 8*(reg>>2) + 4*(lane>>5)
// Swapped QK^T: D = mfma(K_frag, Q_frag) -> lane holds P[q = lane&31][32 keys in 16 regs].
__global__ __launch_bounds__(256) void attn_k(const short* __restrict__ q,
                                              const short* __restrict__ kv,
                                              const short* __restrict__ vt,
                                              short* __restrict__ out){
  // Ks: [64 keys][128 d] rows of 16 chunks(16B), chunk XOR-swizzled by (row&7)
  // Vts: [128 d][64 keys] rows of 8 chunks(16B), chunk XOR-swizzled by (row&7)
  __shared__ __align__(16) short Ks[2][64 * 128];
  __shared__ __align__(16) short Vts[2][128 * 64];
  const int qt = blockIdx.x, bh = blockIdx.y;
  const int b = bh >> 4, h = bh & 15;
  const int tid = threadIdx.x, lane = tid & 63, wid = tid >> 6;
  const int l31 = lane & 31, hi = lane >> 5;
  const int qrow0 = qt * 128 + wid * 32;
  const float c2 = 0.08838834764831845f * 1.4426950408889634f;  // (1/sqrt(128)) * log2(e)
  const int NT = SEQ / 64;

  // Q B-frags: qf[s] = Q[q = qrow0+l31][d = s*16 + hi*8 .. +8]
  bf16x8 qf[8];
  {
    const short* qp = q + (size_t)(b * SEQ + qrow0 + l31) * DIM + h * DHEAD + hi * 8;
    #pragma unroll
    for (int s = 0; s < 8; s++) qf[s] = *(const bf16x8*)(qp + s * 16);
  }

  f32x16 acc[4] = {};              // O[q=crow(reg,hi)][d=dt*32+l31]
  float m2 = -3e38f, l_s = 0.f;    // running max (exp2-domain) and denom, for q = l31

  auto stage = [&](int kt, int bs){
    #pragma unroll
    for (int i = 0; i < 4; i++){
      int cb = (i * 4 + wid) * 64;          // wave-uniform chunk base
      int c  = cb + lane;
      int kr = c >> 4, kj = (c & 15) ^ (kr & 7);
      gl_lds16(kv + (size_t)(b * SEQ + kt * 64 + kr) * 4096 + h * DHEAD + kj * 8,
               &Ks[bs][cb * 8]);
      int vr = c >> 3, vj = (c & 7) ^ (vr & 7);
      gl_lds16(vt + (size_t)(bh * DHEAD + vr) * SEQ + kt * 64 + vj * 8,
               &Vts[bs][cb * 8]);
    }
  };

  stage(0, 0);
  int cur = 0;

  for (int kt = 0; kt < NT; kt++){
    if (kt + 1 < NT){
      stage(kt + 1, cur ^ 1);
      asm volatile("s_waitcnt vmcnt(8)" ::: "memory");
    } else {
      asm volatile("s_waitcnt vmcnt(0)" ::: "memory");
    }
    __builtin_amdgcn_s_barrier();

    const short* Kb = Ks[cur];
    const short* Vb = Vts[cur];

    // ---- QK^T (swapped): two 32-key tiles, 8 d-slices of K=16 each ----
    f32x16 t0 = {0,0,0,0,0,0,0,0,0,0,0,0,0,0,0,0};
    f32x16 t1 = t0;
    {
      const int r0 = l31, r1 = l31 + 32;
      #pragma unroll
      for (int s = 0; s < 8; s++){
        bf16x8 k0 = *(const bf16x8*)&Kb[r0 * 128 + (((2 * s + hi) ^ (r0 & 7)) * 8)];
        bf16x8 k1 = *(const bf16x8*)&Kb[r1 * 128 + (((2 * s + hi) ^ (r1 & 7)) * 8)];
        t0 = __builtin_amdgcn_mfma_f32_32x32x16_bf16(k0, qf[s], t0, 0, 0, 0);
        t1 = __builtin_amdgcn_mfma_f32_32x32x16_bf16(k1, qf[s], t1, 0, 0, 0);
      }
    }

    // ---- online softmax, exp2-domain, defer-max (THR = 8 nat = 11.5 in log2) ----
    float mxr = t0[0];
    #pragma unroll
    for (int i = 1; i < 16; i++) mxr = fmaxf(mxr, t0[i]);
    #pragma unroll
    for (int i = 0; i < 16; i++) mxr = fmaxf(mxr, t1[i]);
    mxr = fmaxf(mxr, __shfl_xor(mxr, 32));
    float mx2 = mxr * c2;
    if (!__all(mx2 <= m2 + 11.5f)){
      float m2n = fmaxf(m2, mx2);
      float al = exp2a(m2 - m2n);
      m2 = m2n;
      l_s *= al;
      #pragma unroll
      for (int reg = 0; reg < 16; reg++){
        float ar = __shfl(al, (reg & 3) + 8 * (reg >> 2) + 4 * hi);
        #pragma unroll
        for (int dt = 0; dt < 4; dt++) acc[dt][reg] *= ar;
      }
    }

    // p = exp2(S*c2 - m2), packed pairwise to bf16
    // w[kt2*8 + pr] = cvtpk(p[2pr], p[2pr+1]) : pr 0,1 -> "a"; 2,3 -> "b"; 4,5 -> "a2"; 6,7 -> "b2"
    float ps = 0.f;
    unsigned w[16];
    #pragma unroll
    for (int pr = 0; pr < 8; pr++){
      float pa_ = exp2a(fmaf(t0[2 * pr], c2, -m2));
      float pb_ = exp2a(fmaf(t0[2 * pr + 1], c2, -m2));
      ps += pa_ + pb_;
      w[pr] = cvtpk(pa_, pb_);
    }
    #pragma unroll
    for (int pr = 0; pr < 8; pr++){
      float pa_ = exp2a(fmaf(t1[2 * pr], c2, -m2));
      float pb_ = exp2a(fmaf(t1[2 * pr + 1], c2, -m2));
      ps += pa_ + pb_;
      w[8 + pr] = cvtpk(pa_, pb_);
    }
    ps += __shfl_xor(ps, 32);
    l_s += ps;

    // ---- PV: 4 k-slot frags (16 keys each) x 4 d-tiles ----
    // A-frag for k-slot fp: lane needs keys fp*16 + 8*hi + e. Own regs give keys ..+4*hi;
    // the other half's regs give the missing 4-key groups -> half-swap via shfl_xor(32).
    #pragma unroll
    for (int fp = 0; fp < 4; fp++){
      unsigned A0 = w[fp * 4 + 0], A1 = w[fp * 4 + 1];
      unsigned B0 = w[fp * 4 + 2], B1 = w[fp * 4 + 3];
      unsigned xA0 = __shfl_xor((int)A0, 32), xA1 = __shfl_xor((int)A1, 32);
      unsigned xB0 = __shfl_xor((int)B0, 32), xB1 = __shfl_xor((int)B1, 32);
      u32x4 fw;
      fw[0] = hi ? xB0 : A0;
      fw[1] = hi ? xB1 : A1;
      fw[2] = hi ? B0 : xA0;
      fw[3] = hi ? B1 : xA1;
      union { u32x4 u; bf16x8 v; } pc; pc.u = fw;
      #pragma unroll
      for (int dt = 0; dt < 4; dt++){
        int vr = dt * 32 + l31;
        bf16x8 vb = *(const bf16x8*)&Vb[vr * 64 + (((2 * fp + hi) ^ (vr & 7)) * 8)];
        acc[dt] = __builtin_amdgcn_mfma_f32_32x32x16_bf16(pc.v, vb, acc[dt], 0, 0, 0);
      }
    }

    asm volatile("s_waitcnt lgkmcnt(0)" ::: "memory");
    __builtin_amdgcn_s_barrier();
    cur ^= 1;
  }

  // ---- epilogue: O / l, write bf16 ----
  float inv = 1.0f / l_s;
  #pragma unroll
  for (int reg = 0; reg < 16; reg++){
    int cr = (reg & 3) + 8 * (reg >> 2) + 4 * hi;
    float li = __shfl(inv, cr);
    int row = qrow0 + cr;
    #pragma unroll
    for (int dt = 0; dt < 4; dt++)
      out[(size_t)(b * SEQ + row) * DIM + h * DHEAD + dt * 32 + l31] = f2bf(acc[dt][reg] * li);
  }
}

// ---------------- launch ----------------
extern "C" void kernel_launch(void* const* d_in, const int* in_sizes, int n_in,
                              void* d_out, int out_size, void* d_ws, size_t ws_size,
                              hipStream_t stream) {
  (void)in_sizes; (void)n_in; (void)out_size; (void)ws_size;
  const float* tokens = (const float*)d_in[0];
  const float* normw  = (const float*)d_in[1];
  const float* wq     = (const float*)d_in[2];
  const float* wkv    = (const float*)d_in[3];
  const float* wout   = (const float*)d_in[4];
  float* outp = (float*)d_out;
  char* ws = (char*)d_ws;

  short* x     = (short*)(ws + 0);                    // 8192*2048*2   = 33554432
  short* wqt   = (short*)(ws + 33554432);             // 2048*2048*2   = 8388608
  short* wkvt  = (short*)(ws + 41943040);             // 4096*2048*2   = 16777216
  short* woutt = (short*)(ws + 58720256);             // 2048*2048*2   = 8388608
  short* qb    = (short*)(ws + 67108864);             // 8192*2048*2   = 33554432 (also attn out)
  short* kvb   = (short*)(ws + 100663296);            // 8192*4096*2   = 67108864
  short* vtb   = (short*)(ws + 167772160);            // 64*128*2048*2 = 33554432  (end 201326592)

  rmsnorm_cast_k<<<dim3(MROWS), dim3(256), 0, stream>>>(tokens, normw, x);
  wtrans_k<<<dim3(2048/64, 2048/64), dim3(256), 0, stream>>>(wq,   wqt,   2048, 2048);
  wtrans_k<<<dim3(4096/64, 2048/64), dim3(256), 0, stream>>>(wkv,  wkvt,  2048, 4096);
  wtrans_k<<<dim3(2048/64, 2048/64), dim3(256), 0, stream>>>(wout, woutt, 2048, 2048);
  gemm_bt_k<short><<<dim3(2048/128, MROWS/128), dim3(256), 0, stream>>>(x, wqt,  qb,  MROWS, 2048, 2048);
  gemm_bt_k<short><<<dim3(4096/128, MROWS/128), dim3(256), 0, stream>>>(x, wkvt, kvb, MROWS, 4096, 2048);
  vtrans_k<<<dim3(SEQ/64, DHEAD/64, BATCH*HEADS), dim3(256), 0, stream>>>(kvb, vtb);
  attn_k<<<dim3(SEQ/128, BATCH*HEADS), dim3(256), 0, stream>>>(qb, kvb, vtb, qb);
  gemm_bt_k<float><<<dim3(2048/128, MROWS/128), dim3(256), 0, stream>>>(qb, woutt, outp, MROWS, 2048, 2048);
}

// Round 4
// 610.864 us; speedup vs baseline: 1.5115x; 1.1232x over previous
//
#include <hip/hip_runtime.h>
#include <hip/hip_bf16.h>
#include <stdint.h>

#define SEQ   2048
#define DIM   2048
#define HEADS 16
#define DHEAD 128
#define BATCH 4
#define MROWS (BATCH*SEQ)   // 8192

typedef short bf16x8 __attribute__((ext_vector_type(8)));
typedef float f32x4  __attribute__((ext_vector_type(4)));
typedef float f32x16 __attribute__((ext_vector_type(16)));
typedef unsigned short u16x8 __attribute__((ext_vector_type(8)));
typedef unsigned int u32x4 __attribute__((ext_vector_type(4)));

__device__ __forceinline__ short f2bf(float f){
  union { float fv; unsigned u; } x; x.fv = f;
  unsigned r = x.u + 0x7fffu + ((x.u >> 16) & 1u);
  return (short)(r >> 16);
}

__device__ __forceinline__ unsigned cvtpk(float lo, float hi){
  unsigned r; asm("v_cvt_pk_bf16_f32 %0, %1, %2" : "=v"(r) : "v"(lo), "v"(hi)); return r;
}

__device__ __forceinline__ float exp2a(float x){
#if __has_builtin(__builtin_amdgcn_exp2f)
  return __builtin_amdgcn_exp2f(x);
#else
  return exp2f(x);
#endif
}

__device__ __forceinline__ void gl_lds16(const void* g, void* l){
  __builtin_amdgcn_global_load_lds((const __attribute__((address_space(1))) void*)g,
                                   (__attribute__((address_space(3))) void*)l, 16, 0, 0);
}

// ---------------- RMSNorm (fp32) + cast to bf16 ----------------
__global__ __launch_bounds__(256) void rmsnorm_cast_k(const float* __restrict__ tok,
                                                      const float* __restrict__ w,
                                                      short* __restrict__ x){
  const int row = blockIdx.x;
  const float4* r4 = (const float4*)(tok + (size_t)row * DIM);
  float4 a = r4[threadIdx.x * 2];
  float4 b = r4[threadIdx.x * 2 + 1];
  float ss = a.x*a.x + a.y*a.y + a.z*a.z + a.w*a.w
           + b.x*b.x + b.y*b.y + b.z*b.z + b.w*b.w;
  #pragma unroll
  for (int m = 1; m < 64; m <<= 1) ss += __shfl_xor(ss, m, 64);
  __shared__ float red[4];
  if ((threadIdx.x & 63) == 0) red[threadIdx.x >> 6] = ss;
  __syncthreads();
  float tot = red[0] + red[1] + red[2] + red[3];
  float rs = rsqrtf(tot * (1.0f / DIM) + 1.1920929e-07f);
  const float4* w4 = (const float4*)w;
  float4 wa = w4[threadIdx.x * 2];
  float4 wb = w4[threadIdx.x * 2 + 1];
  u16x8 o;
  o[0] = (unsigned short)f2bf(a.x * rs * wa.x);
  o[1] = (unsigned short)f2bf(a.y * rs * wa.y);
  o[2] = (unsigned short)f2bf(a.z * rs * wa.z);
  o[3] = (unsigned short)f2bf(a.w * rs * wa.w);
  o[4] = (unsigned short)f2bf(b.x * rs * wb.x);
  o[5] = (unsigned short)f2bf(b.y * rs * wb.y);
  o[6] = (unsigned short)f2bf(b.z * rs * wb.z);
  o[7] = (unsigned short)f2bf(b.w * rs * wb.w);
  *(u16x8*)(x + (size_t)row * DIM + threadIdx.x * 8) = o;
}

// ---------------- weight cast + transpose: w[K][N] fp32 -> wt[N][K] bf16 ----------------
__global__ __launch_bounds__(256) void wtrans_k(const float* __restrict__ w,
                                                short* __restrict__ wt,
                                                int K, int N){
  __shared__ float tile[64][65];
  const int r0 = blockIdx.y * 64;   // K direction
  const int c0 = blockIdx.x * 64;   // N direction
  const int t = threadIdx.x;
  #pragma unroll
  for (int i = 0; i < 16; i++){
    int e = i * 256 + t; int r = e >> 6, c = e & 63;
    tile[r][c] = w[(size_t)(r0 + r) * N + c0 + c];
  }
  __syncthreads();
  #pragma unroll
  for (int i = 0; i < 16; i++){
    int e = i * 256 + t; int c = e >> 6, r = e & 63;
    wt[(size_t)(c0 + c) * K + r0 + r] = f2bf(tile[r][c]);
  }
}

// ---------------- V transpose: kv[b*S+n][4096] (v half) -> vt[(bh*128+d)][S] ----------------
__global__ __launch_bounds__(256) void vtrans_k(const short* __restrict__ kv,
                                                short* __restrict__ vt){
  __shared__ short tile[64][65];
  const int n0 = blockIdx.x * 64;
  const int d0 = blockIdx.y * 64;
  const int bh = blockIdx.z;
  const int b = bh >> 4, h = bh & 15;
  const int t = threadIdx.x;
  #pragma unroll
  for (int i = 0; i < 16; i++){
    int e = i * 256 + t; int r = e >> 6, c = e & 63;   // r = n, c = d
    tile[r][c] = kv[(size_t)(b * SEQ + n0 + r) * 4096 + 2048 + h * DHEAD + d0 + c];
  }
  __syncthreads();
  #pragma unroll
  for (int i = 0; i < 16; i++){
    int e = i * 256 + t; int c = e >> 6, r = e & 63;   // c = d, r = n
    vt[(size_t)(bh * DHEAD + d0 + c) * SEQ + n0 + r] = tile[r][c];
  }
}

// ---------------- 256x256 GEMM, BK=32, 4-slot LDS ring, depth-3 prefetch ----------------
// C[M][N] = A[M][K] * Bt[N][K]^T, bf16 in, OutT out.
// 8 waves (2 M x 4 N), per-wave 128x64 output, 32x32x16 MFMA.
// LDS: chunk-XOR swizzle ch ^= (row>>1)&3 (both stage-source and ds_read sides).
// Pipeline: stage(t+3) -> compute(t) -> vmcnt(8)+barrier (retires exactly tile t+1's 4 loads).
__device__ __forceinline__ void storeC(float* C, size_t idx, float v){ C[idx] = v; }
__device__ __forceinline__ void storeC(short* C, size_t idx, float v){ C[idx] = f2bf(v); }

template<typename OutT>
__global__ __launch_bounds__(512, 2) void gemm256_k(const short* __restrict__ A,
                                                    const short* __restrict__ Bt,
                                                    OutT* __restrict__ C,
                                                    int M, int N, int K, int lgntn){
  __shared__ __align__(16) short As[4][256 * 32];
  __shared__ __align__(16) short Bs[4][256 * 32];
  const int nwg = gridDim.x;
  const int bid = blockIdx.x;
  const int o = (bid & 7) * (nwg >> 3) + (bid >> 3);   // XCD-contiguous remap (nwg%8==0)
  const int bm = o >> lgntn, bn = o & ((1 << lgntn) - 1);
  const int m0 = bm << 8, n0 = bn << 8;
  const int tid = threadIdx.x, lane = tid & 63, wid = tid >> 6;
  const int l31 = lane & 31, hi = lane >> 5;
  const int wr = wid >> 2, wc = wid & 3;
  const int NT = K >> 5;                                // K/32

  f32x16 acc[4][2] = {};

  auto stage = [&](int t){
    const int slot = t & 3;
    const size_t kbase = (size_t)t << 5;
    #pragma unroll
    for (int i = 0; i < 2; i++){
      int c = i * 512 + tid;
      int row = c >> 2;
      int j = (c & 3) ^ ((row >> 1) & 3);
      gl_lds16(A + (size_t)(m0 + row) * K + kbase + j * 8,
               &As[slot][(i * 512 + wid * 64) * 8]);
    }
    #pragma unroll
    for (int i = 0; i < 2; i++){
      int c = i * 512 + tid;
      int row = c >> 2;
      int j = (c & 3) ^ ((row >> 1) & 3);
      gl_lds16(Bt + (size_t)(n0 + row) * K + kbase + j * 8,
               &Bs[slot][(i * 512 + wid * 64) * 8]);
    }
  };

  auto compute = [&](int t){
    const short* Ab = As[t & 3];
    const short* Bb = Bs[t & 3];
    bf16x8 af[4][2], bfv[2][2];
    #pragma unroll
    for (int mb = 0; mb < 4; mb++){
      int row = wr * 128 + mb * 32 + l31;
      #pragma unroll
      for (int ks = 0; ks < 2; ks++){
        int ch = (ks * 2 + hi) ^ ((row >> 1) & 3);
        af[mb][ks] = *(const bf16x8*)&Ab[row * 32 + ch * 8];
      }
    }
    #pragma unroll
    for (int nb = 0; nb < 2; nb++){
      int row = wc * 64 + nb * 32 + l31;
      #pragma unroll
      for (int ks = 0; ks < 2; ks++){
        int ch = (ks * 2 + hi) ^ ((row >> 1) & 3);
        bfv[nb][ks] = *(const bf16x8*)&Bb[row * 32 + ch * 8];
      }
    }
    __builtin_amdgcn_s_setprio(1);
    #pragma unroll
    for (int mb = 0; mb < 4; mb++)
      #pragma unroll
      for (int nb = 0; nb < 2; nb++)
        #pragma unroll
        for (int ks = 0; ks < 2; ks++)
          acc[mb][nb] = __builtin_amdgcn_mfma_f32_32x32x16_bf16(af[mb][ks], bfv[nb][ks],
                                                                acc[mb][nb], 0, 0, 0);
    __builtin_amdgcn_s_setprio(0);
  };

  stage(0); stage(1); stage(2);                          // 12 loads in flight
  asm volatile("s_waitcnt vmcnt(8)" ::: "memory");       // tile 0 complete
  __builtin_amdgcn_s_barrier();

  for (int t = 0; t < NT; t++){
    if (t + 3 < NT) stage(t + 3);
    compute(t);
    if (t + 1 < NT){
      if (t + 3 < NT)      asm volatile("s_waitcnt vmcnt(8)" ::: "memory");
      else if (t + 2 < NT) asm volatile("s_waitcnt vmcnt(4)" ::: "memory");
      else                 asm volatile("s_waitcnt vmcnt(0)" ::: "memory");
      __builtin_amdgcn_s_barrier();
    }
  }

  #pragma unroll
  for (int mb = 0; mb < 4; mb++)
    #pragma unroll
    for (int nb = 0; nb < 2; nb++)
      #pragma unroll
      for (int reg = 0; reg < 16; reg++){
        int r = (reg & 3) + 8 * (reg >> 2) + 4 * hi;
        int row = m0 + wr * 128 + mb * 32 + r;
        int col = n0 + wc * 64 + nb * 32 + l31;
        storeC(C, (size_t)row * N + col, acc[mb][nb][reg]);
      }
}

// ---------------- Flash attention: 4 waves x 32 q-rows, 32x32x16 MFMA, swapped QK^T ---------
__global__ __launch_bounds__(256) void attn_k(const short* __restrict__ q,
                                              const short* __restrict__ kv,
                                              const short* __restrict__ vt,
                                              short* __restrict__ out){
  __shared__ __align__(16) short Ks[2][64 * 128];
  __shared__ __align__(16) short Vts[2][128 * 64];
  const int qt = blockIdx.x, bh = blockIdx.y;
  const int b = bh >> 4, h = bh & 15;
  const int tid = threadIdx.x, lane = tid & 63, wid = tid >> 6;
  const int l31 = lane & 31, hi = lane >> 5;
  const int qrow0 = qt * 128 + wid * 32;
  const float c2 = 0.08838834764831845f * 1.4426950408889634f;  // (1/sqrt(128)) * log2(e)
  const int NT = SEQ / 64;

  bf16x8 qf[8];
  {
    const short* qp = q + (size_t)(b * SEQ + qrow0 + l31) * DIM + h * DHEAD + hi * 8;
    #pragma unroll
    for (int s = 0; s < 8; s++) qf[s] = *(const bf16x8*)(qp + s * 16);
  }

  f32x16 acc[4] = {};
  float m2 = -3e38f, l_s = 0.f;

  auto stage = [&](int kt, int bs){
    #pragma unroll
    for (int i = 0; i < 4; i++){
      int cb = (i * 4 + wid) * 64;
      int c  = cb + lane;
      int kr = c >> 4, kj = (c & 15) ^ (kr & 7);
      gl_lds16(kv + (size_t)(b * SEQ + kt * 64 + kr) * 4096 + h * DHEAD + kj * 8,
               &Ks[bs][cb * 8]);
      int vr = c >> 3, vj = (c & 7) ^ (vr & 7);
      gl_lds16(vt + (size_t)(bh * DHEAD + vr) * SEQ + kt * 64 + vj * 8,
               &Vts[bs][cb * 8]);
    }
  };

  stage(0, 0);
  int cur = 0;

  for (int kt = 0; kt < NT; kt++){
    if (kt + 1 < NT){
      stage(kt + 1, cur ^ 1);
      asm volatile("s_waitcnt vmcnt(8)" ::: "memory");
    } else {
      asm volatile("s_waitcnt vmcnt(0)" ::: "memory");
    }
    __builtin_amdgcn_s_barrier();

    const short* Kb = Ks[cur];
    const short* Vb = Vts[cur];

    f32x16 t0 = {0,0,0,0,0,0,0,0,0,0,0,0,0,0,0,0};
    f32x16 t1 = t0;
    {
      const int r0 = l31, r1 = l31 + 32;
      #pragma unroll
      for (int s = 0; s < 8; s++){
        bf16x8 k0 = *(const bf16x8*)&Kb[r0 * 128 + (((2 * s + hi) ^ (r0 & 7)) * 8)];
        bf16x8 k1 = *(const bf16x8*)&Kb[r1 * 128 + (((2 * s + hi) ^ (r1 & 7)) * 8)];
        t0 = __builtin_amdgcn_mfma_f32_32x32x16_bf16(k0, qf[s], t0, 0, 0, 0);
        t1 = __builtin_amdgcn_mfma_f32_32x32x16_bf16(k1, qf[s], t1, 0, 0, 0);
      }
    }

    float mxr = t0[0];
    #pragma unroll
    for (int i = 1; i < 16; i++) mxr = fmaxf(mxr, t0[i]);
    #pragma unroll
    for (int i = 0; i < 16; i++) mxr = fmaxf(mxr, t1[i]);
    mxr = fmaxf(mxr, __shfl_xor(mxr, 32));
    float mx2 = mxr * c2;
    if (!__all(mx2 <= m2 + 11.5f)){
      float m2n = fmaxf(m2, mx2);
      float al = exp2a(m2 - m2n);
      m2 = m2n;
      l_s *= al;
      #pragma unroll
      for (int reg = 0; reg < 16; reg++){
        float ar = __shfl(al, (reg & 3) + 8 * (reg >> 2) + 4 * hi);
        #pragma unroll
        for (int dt = 0; dt < 4; dt++) acc[dt][reg] *= ar;
      }
    }

    float ps = 0.f;
    unsigned w[16];
    #pragma unroll
    for (int pr = 0; pr < 8; pr++){
      float pa_ = exp2a(fmaf(t0[2 * pr], c2, -m2));
      float pb_ = exp2a(fmaf(t0[2 * pr + 1], c2, -m2));
      ps += pa_ + pb_;
      w[pr] = cvtpk(pa_, pb_);
    }
    #pragma unroll
    for (int pr = 0; pr < 8; pr++){
      float pa_ = exp2a(fmaf(t1[2 * pr], c2, -m2));
      float pb_ = exp2a(fmaf(t1[2 * pr + 1], c2, -m2));
      ps += pa_ + pb_;
      w[8 + pr] = cvtpk(pa_, pb_);
    }
    ps += __shfl_xor(ps, 32);
    l_s += ps;

    #pragma unroll
    for (int fp = 0; fp < 4; fp++){
      unsigned A0 = w[fp * 4 + 0], A1 = w[fp * 4 + 1];
      unsigned B0 = w[fp * 4 + 2], B1 = w[fp * 4 + 3];
      unsigned xA0 = __shfl_xor((int)A0, 32), xA1 = __shfl_xor((int)A1, 32);
      unsigned xB0 = __shfl_xor((int)B0, 32), xB1 = __shfl_xor((int)B1, 32);
      u32x4 fw;
      fw[0] = hi ? xB0 : A0;
      fw[1] = hi ? xB1 : A1;
      fw[2] = hi ? B0 : xA0;
      fw[3] = hi ? B1 : xA1;
      union { u32x4 u; bf16x8 v; } pc; pc.u = fw;
      #pragma unroll
      for (int dt = 0; dt < 4; dt++){
        int vr = dt * 32 + l31;
        bf16x8 vb = *(const bf16x8*)&Vb[vr * 64 + (((2 * fp + hi) ^ (vr & 7)) * 8)];
        acc[dt] = __builtin_amdgcn_mfma_f32_32x32x16_bf16(pc.v, vb, acc[dt], 0, 0, 0);
      }
    }

    asm volatile("s_waitcnt lgkmcnt(0)" ::: "memory");
    __builtin_amdgcn_s_barrier();
    cur ^= 1;
  }

  float inv = 1.0f / l_s;
  #pragma unroll
  for (int reg = 0; reg < 16; reg++){
    int cr = (reg & 3) + 8 * (reg >> 2) + 4 * hi;
    float li = __shfl(inv, cr);
    int row = qrow0 + cr;
    #pragma unroll
    for (int dt = 0; dt < 4; dt++)
      out[(size_t)(b * SEQ + row) * DIM + h * DHEAD + dt * 32 + l31] = f2bf(acc[dt][reg] * li);
  }
}

// ---------------- launch ----------------
extern "C" void kernel_launch(void* const* d_in, const int* in_sizes, int n_in,
                              void* d_out, int out_size, void* d_ws, size_t ws_size,
                              hipStream_t stream) {
  (void)in_sizes; (void)n_in; (void)out_size; (void)ws_size;
  const float* tokens = (const float*)d_in[0];
  const float* normw  = (const float*)d_in[1];
  const float* wq     = (const float*)d_in[2];
  const float* wkv    = (const float*)d_in[3];
  const float* wout   = (const float*)d_in[4];
  float* outp = (float*)d_out;
  char* ws = (char*)d_ws;

  short* x     = (short*)(ws + 0);                    // 8192*2048*2   = 33554432
  short* wqt   = (short*)(ws + 33554432);             // 2048*2048*2   = 8388608
  short* wkvt  = (short*)(ws + 41943040);             // 4096*2048*2   = 16777216
  short* woutt = (short*)(ws + 58720256);             // 2048*2048*2   = 8388608
  short* qb    = (short*)(ws + 67108864);             // 8192*2048*2   = 33554432 (also attn out)
  short* kvb   = (short*)(ws + 100663296);            // 8192*4096*2   = 67108864
  short* vtb   = (short*)(ws + 167772160);            // 64*128*2048*2 = 33554432  (end 201326592)

  rmsnorm_cast_k<<<dim3(MROWS), dim3(256), 0, stream>>>(tokens, normw, x);
  wtrans_k<<<dim3(2048/64, 2048/64), dim3(256), 0, stream>>>(wq,   wqt,   2048, 2048);
  wtrans_k<<<dim3(4096/64, 2048/64), dim3(256), 0, stream>>>(wkv,  wkvt,  2048, 4096);
  wtrans_k<<<dim3(2048/64, 2048/64), dim3(256), 0, stream>>>(wout, woutt, 2048, 2048);
  gemm256_k<short><<<dim3((MROWS/256)*(2048/256)), dim3(512), 0, stream>>>(x, wqt,  qb,  MROWS, 2048, 2048, 3);
  gemm256_k<short><<<dim3((MROWS/256)*(4096/256)), dim3(512), 0, stream>>>(x, wkvt, kvb, MROWS, 4096, 2048, 4);
  vtrans_k<<<dim3(SEQ/64, DHEAD/64, BATCH*HEADS), dim3(256), 0, stream>>>(kvb, vtb);
  attn_k<<<dim3(SEQ/128, BATCH*HEADS), dim3(256), 0, stream>>>(qb, kvb, vtb, qb);
  gemm256_k<float><<<dim3((MROWS/256)*(2048/256)), dim3(512), 0, stream>>>(qb, woutt, outp, MROWS, 2048, 2048, 3);
}